// Round 3
// baseline (318.609 us; speedup 1.0000x reference)
//
#include <hip/hip_runtime.h>

// VolumeRenderer: N=65536 rays, L=192 samples.
//   delta[l] = depth[l+1]-depth[l] (last = 1e10)
//   alpha = 1 - exp(-relu(sigma)*delta)
//   w     = alpha * (1 - alpha + 1e-10)      (cumprod over size-1 axis = identity)
//   color = sum_l sigmoid(rgb[l]) * w[l]     -> (N,3)
//   depth_out = sum_l w[l]*depth[l]          -> (N,1)
//
// R1/R2 lesson: wave-per-ray needs 29 ds_bpermute + butterfly reduction per ray;
// both variants pinned at ~93 us with ALL pipes <20% busy -> latency-bound on the
// cross-lane dependent chain. R3: thread-per-half-ray. No shuffles (except one
// final pair-combine), no LDS, no reduction; 10 independent float4 loads per
// 8-sample chunk give deep MLP; 4 accumulators live in registers.

constexpr int L     = 192;
constexpr int SPLIT = 2;          // threads per ray
constexpr int SL    = L / SPLIT;  // 96 samples per thread
constexpr int NCH   = SL / 8;     // 12 chunks of 8 samples

__device__ __forceinline__ float fast_sigmoid(float x) {
    return __builtin_amdgcn_rcpf(1.0f + __expf(-x));
}

__global__ __launch_bounds__(256) void volrender_kernel(
    const float* __restrict__ depth, const float* __restrict__ rgb,
    const float* __restrict__ sigma, float* __restrict__ out, int n_rays)
{
    const int t    = blockIdx.x * blockDim.x + threadIdx.x;
    const int ray  = t >> 1;          // lanes 2k,2k+1 share a ray (same wave)
    const int half = t & 1;           // 0: samples 0..95, 1: samples 96..191

    const size_t sbase = (size_t)ray * L + half * SL;
    const float4* dp = (const float4*)(depth + sbase);       // 384B-aligned
    const float4* sp = (const float4*)(sigma + sbase);
    const float4* cp = (const float4*)(rgb + sbase * 3);     // 1152B-aligned

    // boundary: half 0's last delta needs depth[96]; half 1 pads with 1e10
    const float bound_d = (half == 0) ? depth[sbase + SL] : 0.0f;

    float cr = 0.f, cg = 0.f, cb = 0.f, dacc = 0.f;
    // carried sample (prev): ps=0 -> alpha=0 -> w=0, so first finish is a no-op
    float pd = 0.f, ps = 0.f, pr = 0.f, pg = 0.f, pb = 0.f;

    auto contribute = [&](float s, float delta, float r, float g, float b, float d) {
        float a = 1.0f - __expf(-fmaxf(s, 0.0f) * delta);
        float w = a * (1.0f - a + 1e-10f);
        cr += fast_sigmoid(r) * w;
        cg += fast_sigmoid(g) * w;
        cb += fast_sigmoid(b) * w;
        dacc += w * d;
    };

    #pragma unroll 2
    for (int c = 0; c < NCH; ++c) {
        // 10 independent float4 loads for this chunk (8 samples)
        float4 d0 = dp[c * 2],     d1 = dp[c * 2 + 1];
        float4 g0 = sp[c * 2],     g1 = sp[c * 2 + 1];
        float4 c0 = cp[c * 6 + 0], c1 = cp[c * 6 + 1], c2 = cp[c * 6 + 2];
        float4 c3 = cp[c * 6 + 3], c4 = cp[c * 6 + 4], c5 = cp[c * 6 + 5];

        // finish carried sample: its delta needs this chunk's first depth
        contribute(ps, d0.x - pd, pr, pg, pb, pd);
        // samples 0..6 of this chunk (sample 7 becomes the carry)
        contribute(g0.x, d0.y - d0.x, c0.x, c0.y, c0.z, d0.x);
        contribute(g0.y, d0.z - d0.y, c0.w, c1.x, c1.y, d0.y);
        contribute(g0.z, d0.w - d0.z, c1.z, c1.w, c2.x, d0.z);
        contribute(g0.w, d1.x - d0.w, c2.y, c2.z, c2.w, d0.w);
        contribute(g1.x, d1.y - d1.x, c3.x, c3.y, c3.z, d1.x);
        contribute(g1.y, d1.z - d1.y, c3.w, c4.x, c4.y, d1.y);
        contribute(g1.z, d1.w - d1.z, c4.z, c4.w, c5.x, d1.z);
        pd = d1.w; ps = g1.w; pr = c5.y; pg = c5.z; pb = c5.w;
    }

    // final carried sample of this half
    const float fdelta = (half == 0) ? (bound_d - pd) : 1e10f;
    contribute(ps, fdelta, pr, pg, pb, pd);

    // combine the two halves (adjacent lanes, same wave)
    cr   += __shfl_xor(cr, 1);
    cg   += __shfl_xor(cg, 1);
    cb   += __shfl_xor(cb, 1);
    dacc += __shfl_xor(dacc, 1);

    if (half == 0) {
        out[ray * 3 + 0] = cr;
        out[ray * 3 + 1] = cg;
        out[ray * 3 + 2] = cb;
        out[(size_t)n_rays * 3 + ray] = dacc;
    }
}

extern "C" void kernel_launch(void* const* d_in, const int* in_sizes, int n_in,
                              void* d_out, int out_size, void* d_ws, size_t ws_size,
                              hipStream_t stream) {
    const float* depth = (const float*)d_in[0];
    const float* rgb   = (const float*)d_in[1];
    const float* sigma = (const float*)d_in[2];
    float* out = (float*)d_out;
    const int n_rays  = in_sizes[0] / L;             // 65536
    const int threads = n_rays * SPLIT;              // 131072
    volrender_kernel<<<threads / 256, 256, 0, stream>>>(depth, rgb, sigma, out, n_rays);
}

// Round 5
// 275.440 us; speedup vs baseline: 1.1567x; 1.1567x over previous
//
#include <hip/hip_runtime.h>

// VolumeRenderer: N=65536 rays, L=192 samples. fp32.
//   delta[l] = depth[l+1]-depth[l] (last = 1e10)
//   alpha = 1 - exp(-relu(sigma)*delta);  w = alpha*(1-alpha+1e-10)
//   color = sum_l sigmoid(rgb)*w -> (N,3);  depth_out = sum_l w*depth -> (N,1)
//
// History: R1/R2 wave-per-ray coalesced = 93us, FETCH 126MB, all pipes idle,
// VGPR=16 (compiler serialized loads -> no MLP) + 29 ds_bpermute/ray tail.
// R3 thread-sequential = 3.1x over-fetch (FETCH 394MB), 137us, but proved the
// memory pipeline sustains ~3TB/s when 10 loads are in flight.
// R4/R5: R1's coalesced mapping + 18 loads issued up-front (sched_barrier pins,
// launch_bounds(256,4) allows 128 VGPR) + ZERO ds ops: delta via shifted
// global re-load (L1-hit), reduction via DPP row_shr/row_bcast (pure VALU).
// R4 failed to compile: update_dpp ctrl must be a constant -> templated.

constexpr int L = 192;

__device__ __forceinline__ float fast_sigmoid(float x) {
    return __builtin_amdgcn_rcpf(1.0f + __expf(-x));
}

template <int CTRL>
__device__ __forceinline__ float dpp_add(float x) {
    int s = __builtin_amdgcn_update_dpp(0, __builtin_bit_cast(int, x),
                                        CTRL, 0xf, 0xf, true);
    return x + __builtin_bit_cast(float, s);
}

// 64-lane sum; result valid in lane 63. gfx9/CDNA DPP sequence, no LDS.
__device__ __forceinline__ float wave_sum63(float x) {
    x = dpp_add<0x111>(x);  // row_shr:1
    x = dpp_add<0x112>(x);  // row_shr:2
    x = dpp_add<0x114>(x);  // row_shr:4
    x = dpp_add<0x118>(x);  // row_shr:8   -> lane 15 of each row = row sum
    x = dpp_add<0x142>(x);  // row_bcast:15 -> rows 1,3 += rows 0,2 sums
    x = dpp_add<0x143>(x);  // row_bcast:31 -> rows 2,3 += (row0+row1) sum
    return x;               // lane 63 = total
}

__global__ __launch_bounds__(256, 4) void volrender_kernel(
    const float* __restrict__ depth, const float* __restrict__ rgb,
    const float* __restrict__ sigma, float* __restrict__ out, int n_rays)
{
    const int lane = threadIdx.x & 63;
    const int ray  = (blockIdx.x << 2) + (threadIdx.x >> 6);  // wave = ray
    const size_t base = (size_t)ray * L;

    const float* dp = depth + base;
    const float* sp = sigma + base;
    const float* cp = rgb + base * 3;

    // ---- ALL 18 global loads issued up-front (deep MLP) ----
    float d0 = dp[lane], d1 = dp[lane + 64], d2 = dp[lane + 128];
    // shifted depth for delta; same cache lines, L1-served; clamp last addr
    float e0 = dp[lane + 1], e1 = dp[lane + 65];
    float e2 = dp[lane + 129 > 191 ? 191 : lane + 129];
    float s0 = sp[lane], s1 = sp[lane + 64], s2 = sp[lane + 128];
    const int i0 = 3 * lane, i1 = i0 + 192, i2 = i0 + 384;
    float r0 = cp[i0], g0 = cp[i0 + 1], b0 = cp[i0 + 2];
    float r1 = cp[i1], g1 = cp[i1 + 1], b1 = cp[i1 + 2];
    float r2 = cp[i2], g2 = cp[i2 + 1], b2 = cp[i2 + 2];
    __builtin_amdgcn_sched_barrier(0);   // keep all loads above all uses

    // ---- per-sample math (no cross-lane ops) ----
    float dl0 = e0 - d0;
    float dl1 = e1 - d1;
    float dl2 = (lane == 63) ? 1e10f : (e2 - d2);   // sample 191: delta = 1e10

    float a0 = 1.0f - __expf(-fmaxf(s0, 0.0f) * dl0);
    float a1 = 1.0f - __expf(-fmaxf(s1, 0.0f) * dl1);
    float a2 = 1.0f - __expf(-fmaxf(s2, 0.0f) * dl2);
    float w0 = a0 * (1.0f - a0 + 1e-10f);
    float w1 = a1 * (1.0f - a1 + 1e-10f);
    float w2 = a2 * (1.0f - a2 + 1e-10f);

    float cr = fast_sigmoid(r0) * w0 + fast_sigmoid(r1) * w1 + fast_sigmoid(r2) * w2;
    float cg = fast_sigmoid(g0) * w0 + fast_sigmoid(g1) * w1 + fast_sigmoid(g2) * w2;
    float cb = fast_sigmoid(b0) * w0 + fast_sigmoid(b1) * w1 + fast_sigmoid(b2) * w2;
    float dd = w0 * d0 + w1 * d1 + w2 * d2;

    // ---- pure-VALU wave reduction (no bpermute, no LDS) ----
    cr = wave_sum63(cr);
    cg = wave_sum63(cg);
    cb = wave_sum63(cb);
    dd = wave_sum63(dd);

    if (lane == 63) {
        out[ray * 3 + 0] = cr;
        out[ray * 3 + 1] = cg;
        out[ray * 3 + 2] = cb;
        out[(size_t)n_rays * 3 + ray] = dd;   // depth block follows color block
    }
}

extern "C" void kernel_launch(void* const* d_in, const int* in_sizes, int n_in,
                              void* d_out, int out_size, void* d_ws, size_t ws_size,
                              hipStream_t stream) {
    const float* depth = (const float*)d_in[0];
    const float* rgb   = (const float*)d_in[1];
    const float* sigma = (const float*)d_in[2];
    float* out = (float*)d_out;
    const int n_rays = in_sizes[0] / L;      // 65536
    const int blocks = n_rays / 4;           // 4 rays (waves) per 256-thread block
    volrender_kernel<<<blocks, 256, 0, stream>>>(depth, rgb, sigma, out, n_rays);
}